// Round 15
// baseline (434.077 us; speedup 1.0000x reference)
//
#include <hip/hip_runtime.h>
#include <hip/hip_fp16.h>

#define NN 30000
#define NE 480000
#define CC 32
#define TT 12
#define CT 384            /* C*T */
#define TOT (4 * NN)      /* 120000 tasks */
#define NB  118           /* ceil(TOT/1024) */
#define NSL 8             /* slices per row (96 B each) */
#define SLB96 ((size_t)NN * 96)  /* 2.88 MB per slice array: fits one XCD L2 */
#define GPB 8             /* nodes per gather block */
#define GPM 8             /* nodes per matmul block */
#define RSH2 193          /* matmul LDS row stride in half2 (padded) */
#define NBKT 235          /* CSR buckets: 512 rows each */
#define BCAP 16384        /* staging records per bucket */
#define PAIRS_WORDS ((size_t)4 * NE + 4 * TOT + 32)

typedef unsigned int u32x4 __attribute__((ext_vector_type(4)));
typedef unsigned int u32x2 __attribute__((ext_vector_type(2)));
typedef float f32x2 __attribute__((ext_vector_type(2)));

static __device__ __forceinline__ unsigned int h2u(__half2 h) {
    return __builtin_bit_cast(unsigned int, h);
}
static __device__ __forceinline__ __half2 u2h(unsigned int u) {
    return __builtin_bit_cast(__half2, u);
}

// ---------------- x -> fp16, slice-major (8 slices x 96 B per node row) ----------------
// half2 word w (0..191) of row n -> slice s = w/24, within-slice half2 idx = n*24 + w%24.

__global__ void conv_kernel(const float2* __restrict__ x2, char* __restrict__ xh) {
    int i = blockIdx.x * blockDim.x + threadIdx.x;
    if (i < NN * 192) {
        float2 v = x2[i];
        int n = i / 192, w = i % 192;
        __half2* dst = (__half2*)(xh + (size_t)(w / 24) * SLB96);
        dst[n * 24 + (w % 24)] = __floats2half2_rn(v.x, v.y);
    }
}

// ---------------- CSR build: binned, no random global writes ----------------

__global__ void initcur_kernel(int* __restrict__ g_cur) {
    int t = threadIdx.x;
    if (t < NBKT) g_cur[t] = t * BCAP;
}

__global__ __launch_bounds__(512)
void bin_kernel(const int* __restrict__ ei0, const int* __restrict__ ei1,
                const int* __restrict__ ei2, const int* __restrict__ ei3,
                const float* __restrict__ ew0, const float* __restrict__ ew1,
                const float* __restrict__ ew2, const float* __restrict__ ew3,
                int* __restrict__ g_cur, u32x2* __restrict__ staging) {
    __shared__ int bcnt[NBKT];
    __shared__ int bbase[NBKT];
    const int b = blockIdx.y;
    const int t = threadIdx.x;
    const int e0 = blockIdx.x * 4096;
    const int*   ei = (b == 0) ? ei0 : (b == 1) ? ei1 : (b == 2) ? ei2 : ei3;
    const float* ew = (b == 0) ? ew0 : (b == 1) ? ew1 : (b == 2) ? ew2 : ew3;

    for (int i = t; i < NBKT; i += 512) bcnt[i] = 0;
    __syncthreads();

    int row_[8]; unsigned int pair_[8]; int bkt_[8]; int rank_[8];
#pragma unroll
    for (int i = 0; i < 8; ++i) {
        int e = e0 + i * 512 + t;
        row_[i] = -1;
        if (e < NE) {
            int dst = ei[NE + e];
            int src = ei[e];
            unsigned int w16 = (unsigned int)__half_as_ushort(__float2half_rn(ew[e]));
            row_[i]  = b * NN + dst;
            pair_[i] = (unsigned int)src | (w16 << 16);
            bkt_[i]  = row_[i] >> 9;
            rank_[i] = atomicAdd(&bcnt[bkt_[i]], 1);
        }
    }
    __syncthreads();
    for (int i = t; i < NBKT; i += 512) {
        int cc = bcnt[i];
        bbase[i] = (cc > 0) ? atomicAdd(&g_cur[i], cc) : 0;
    }
    __syncthreads();
#pragma unroll
    for (int i = 0; i < 8; ++i) {
        if (row_[i] >= 0) {
            int pos = bbase[bkt_[i]] + rank_[i];
            if (pos < (bkt_[i] + 1) * BCAP) {
                u32x2 rec; rec.x = (unsigned int)row_[i]; rec.y = pair_[i];
                staging[pos] = rec;
            }
        }
    }
}

__global__ __launch_bounds__(256)
void count_kernel(const int* __restrict__ g_cur, const u32x2* __restrict__ staging,
                  int* __restrict__ cnt) {
    __shared__ int hist[512];
    const int bkt = blockIdx.x;
    const int t = threadIdx.x;
    hist[t] = 0; hist[t + 256] = 0;
    __syncthreads();
    const int row0 = bkt << 9;
    const int n = g_cur[bkt] - bkt * BCAP;
    const u32x2* __restrict__ sg = staging + (size_t)bkt * BCAP;
    for (int i = t; i < n; i += 256)
        atomicAdd(&hist[(int)sg[i].x - row0], 1);
    __syncthreads();
    if (row0 + t < TOT)       cnt[row0 + t]       = hist[t];
    if (row0 + t + 256 < TOT) cnt[row0 + t + 256] = hist[t + 256];
}

// scans over counts padded to multiples of 4 (aligned u32x4 pair loads)
__global__ void scanA_kernel(const int* __restrict__ cnt,
                             int* __restrict__ pre, int* __restrict__ bsum) {
    __shared__ int s[1024];
    int tid = threadIdx.x;
    int i = blockIdx.x * 1024 + tid;
    int v = (i < TOT) ? ((cnt[i] + 3) & ~3) : 0;
    s[tid] = v;
    __syncthreads();
    for (int off = 1; off < 1024; off <<= 1) {
        int t = (tid >= off) ? s[tid - off] : 0;
        __syncthreads();
        s[tid] += t;
        __syncthreads();
    }
    if (i < TOT) pre[i] = s[tid] - v;
    if (tid == 1023) bsum[blockIdx.x] = s[1023];
}

__global__ void scanB_kernel(const int* __restrict__ bsum,
                             int* __restrict__ bbase, int* __restrict__ offs) {
    __shared__ int s[128];
    int tid = threadIdx.x;
    int v = (tid < NB) ? bsum[tid] : 0;
    s[tid] = v;
    __syncthreads();
    for (int off = 1; off < 128; off <<= 1) {
        int t = (tid >= off) ? s[tid - off] : 0;
        __syncthreads();
        s[tid] += t;
        __syncthreads();
    }
    if (tid < NB) bbase[tid] = s[tid] - v;
    if (tid == 127) offs[TOT] = s[127];
}

__global__ void scanC_kernel(const int* __restrict__ pre, const int* __restrict__ bbase,
                             int* __restrict__ offs) {
    int i = blockIdx.x * 1024 + threadIdx.x;
    if (i < TOT) offs[i] = bbase[blockIdx.x] + pre[i];
}

__global__ __launch_bounds__(256)
void sort_kernel(const int* __restrict__ g_cur, const u32x2* __restrict__ staging,
                 const int* __restrict__ offs, unsigned int* __restrict__ pairs) {
    __shared__ int cur[512];
    const int bkt = blockIdx.x;
    const int t = threadIdx.x;
    const int row0 = bkt << 9;
    cur[t]       = (row0 + t < TOT)       ? offs[row0 + t]       : 0;
    cur[t + 256] = (row0 + t + 256 < TOT) ? offs[row0 + t + 256] : 0;
    __syncthreads();
    const int n = g_cur[bkt] - bkt * BCAP;
    const u32x2* __restrict__ sg = staging + (size_t)bkt * BCAP;
    for (int i = t; i < n; i += 256) {
        u32x2 r = sg[i];
        int pos = atomicAdd(&cur[(int)r.x - row0], 1);
        pairs[pos] = r.y;
    }
}

// ---------------- XCD-pinned slice gather (octet-per-task, R11 loop structure) ----------------
// slice = blockIdx.x & 7 -> empirical blockIdx%8 -> XCD round-robin pins slice k to XCD k;
// each XCD's L2 holds exactly its 2.88 MB slice array (perf heuristic only, not correctness).
// wave = 8 octets; octet -> task (node, branch); lane l owns 12 B of the 96-B slice row.

__global__ __launch_bounds__(256, 8)
void gather_kernel(const char* __restrict__ xh, const unsigned int* __restrict__ pairs,
                   const int* __restrict__ offs, const int* __restrict__ cnt,
                   char* __restrict__ agg) {
    const int tid  = threadIdx.x;
    const int lane = tid & 63;
    const int o = lane >> 3, l = lane & 7;
    const int task = (tid >> 6) * 8 + o;                 // 0..31
    const int slice = blockIdx.x & 7;
    const int node = (blockIdx.x >> 3) * GPB + (task >> 2);
    const int branch = task & 3;
    const int row = branch * NN + node;
    const char* __restrict__ xs = xh + (size_t)slice * SLB96 + l * 12;

    const int beg = offs[row];
    const int c   = cnt[row];

    __half2 a0 = u2h(0), a1 = u2h(0), a2 = u2h(0);
    __half2 b0 = u2h(0), b1 = u2h(0), b2 = u2h(0);

    for (int eb = 0; eb < c; eb += 4) {
        u32x4 pw = __builtin_nontemporal_load((const u32x4*)(pairs + beg + eb));
#pragma unroll
        for (int u = 0; u < 4; ++u) {
            unsigned int w32 = (u == 0) ? pw.x : (u == 1) ? pw.y : (u == 2) ? pw.z : pw.w;
            if (eb + u < c) {
                const char* rp = xs + (w32 & 0xFFFFu) * 96;
                uint3 v = *(const uint3*)rp;
                __half2 w2 = __half2half2(__ushort_as_half((unsigned short)(w32 >> 16)));
                if (u & 1) {
                    b0 = __hfma2(w2, u2h(v.x), b0);
                    b1 = __hfma2(w2, u2h(v.y), b1);
                    b2 = __hfma2(w2, u2h(v.z), b2);
                } else {
                    a0 = __hfma2(w2, u2h(v.x), a0);
                    a1 = __hfma2(w2, u2h(v.y), a1);
                    a2 = __hfma2(w2, u2h(v.z), a2);
                }
            }
        }
    }
    char* dst = agg + (size_t)row * 768 + slice * 96 + l * 12;
    __builtin_nontemporal_store(h2u(__hadd2(a0, b0)), (unsigned int*)dst);
    __builtin_nontemporal_store(h2u(__hadd2(a1, b1)), (unsigned int*)(dst + 4));
    __builtin_nontemporal_store(h2u(__hadd2(a2, b2)), (unsigned int*)(dst + 8));
}

// ---------------- streaming matmul: out = bias + sum_b agg_b @ W_b ----------------
// agg row layout is [c][t] halves (slice chunks are contiguous 96-B pieces of it).

__global__ __launch_bounds__(384)
void matmul_kernel(const char* __restrict__ agg,
                   const float* __restrict__ W0, const float* __restrict__ W1,
                   const float* __restrict__ W2, const float* __restrict__ W3,
                   const float* __restrict__ bias, float* __restrict__ out) {
    __shared__ __half2 aggB[32 * RSH2];   // ~24.7 KB
    const int tid = threadIdx.x;
    const int n0 = blockIdx.x * GPM;

    {
        const int r = tid / 12, sub = tid % 12;
        const char* src = agg + (size_t)((r & 3) * NN + n0 + (r >> 2)) * 768 + sub * 64;
        char* dst = (char*)(aggB + r * RSH2) + sub * 64;
#pragma unroll
        for (int q = 0; q < 4; ++q) {
            u32x4 v = __builtin_nontemporal_load((const u32x4*)(src + 16 * q));
            *(u32x4*)(dst + 16 * q) = v;
        }
    }
    __syncthreads();

    const float* Ws[4] = { W0, W1, W2, W3 };
    {
        const int g = tid / 48;
        const int rem = tid % 48;
        const int q = rem / 6;
        const int t2 = rem % 6;
        f32x2 acc[4];
#pragma unroll
        for (int i = 0; i < 4; ++i) { float bv = bias[q * 4 + i]; acc[i].x = bv; acc[i].y = bv; }
#pragma unroll
        for (int b = 0; b < 4; ++b) {
            const float* __restrict__ Wb = Ws[b];
            const __half2* __restrict__ aL = aggB + (g * 4 + b) * RSH2 + t2;
#pragma unroll
            for (int h = 0; h < 2; ++h) {
                float2 row[16];
#pragma unroll
                for (int kk = 0; kk < 16; ++kk)
                    row[kk] = __half22float2(aL[(h * 16 + kk) * 6]);
#pragma unroll
                for (int kk = 0; kk < 16; ++kk) {
#pragma unroll
                    for (int i = 0; i < 4; ++i) {
                        float w = Wb[(h * 16 + kk) * CC + q * 4 + i];
                        acc[i].x = fmaf(w, row[kk].x, acc[i].x);
                        acc[i].y = fmaf(w, row[kk].y, acc[i].y);
                    }
                }
            }
        }
#pragma unroll
        for (int i = 0; i < 4; ++i) {
            f32x2* dst = (f32x2*)&out[(size_t)(n0 + g) * CT + (q * 4 + i) * TT + 2 * t2];
            __builtin_nontemporal_store(acc[i], dst);
        }
    }
}

// ---------------- launch ----------------

extern "C" void kernel_launch(void* const* d_in, const int* in_sizes, int n_in,
                              void* d_out, int out_size, void* d_ws, size_t ws_size,
                              hipStream_t stream) {
    const float* x    = (const float*)d_in[0];
    const float* bias = (const float*)d_in[13];
    const int*   ei[4] = { (const int*)d_in[1], (const int*)d_in[4],
                           (const int*)d_in[7], (const int*)d_in[10] };
    const float* ew[4] = { (const float*)d_in[2], (const float*)d_in[5],
                           (const float*)d_in[8], (const float*)d_in[11] };
    const float* W[4]  = { (const float*)d_in[3], (const float*)d_in[6],
                           (const float*)d_in[9], (const float*)d_in[12] };
    float* out = (float*)d_out;

    char* ws = (char*)d_ws;
    size_t OFF_PAIRS = 0;                                     // padded pairs ~9.6 MB
    size_t OFF_XH    = OFF_PAIRS + PAIRS_WORDS * 4;           // 23.04 MB fp16 x (8 slice arrays)
    size_t OFF_AGG   = OFF_XH    + NSL * SLB96;               // 92.16 MB agg (staging overlay)
    size_t OFF_CNT   = OFF_AGG   + (size_t)TOT * 768;         // TOT int
    size_t OFF_OFFS  = OFF_CNT   + (size_t)TOT * 4;           // TOT+1 int
    size_t OFF_PRE   = OFF_OFFS  + (size_t)(TOT + 1) * 4;     // TOT int
    size_t OFF_BSUM  = OFF_PRE   + (size_t)TOT * 4;           // 128 int
    size_t OFF_BBASE = OFF_BSUM  + (size_t)128 * 4;           // 128 int
    size_t OFF_GCUR  = OFF_BBASE + (size_t)128 * 4;           // NBKT int

    unsigned int* pairs = (unsigned int*)(ws + OFF_PAIRS);
    char*         xh    = ws + OFF_XH;
    char*         agg   = ws + OFF_AGG;
    u32x2*        staging = (u32x2*)(ws + OFF_AGG);           // overlay: dead before gather
    int* cnt   = (int*)(ws + OFF_CNT);
    int* offs  = (int*)(ws + OFF_OFFS);
    int* pre   = (int*)(ws + OFF_PRE);
    int* bsum  = (int*)(ws + OFF_BSUM);
    int* bbase = (int*)(ws + OFF_BBASE);
    int* g_cur = (int*)(ws + OFF_GCUR);

    initcur_kernel<<<1, 256, 0, stream>>>(g_cur);

    dim3 bg((NE + 4095) / 4096, 4);
    bin_kernel<<<bg, 512, 0, stream>>>(ei[0], ei[1], ei[2], ei[3],
                                       ew[0], ew[1], ew[2], ew[3],
                                       g_cur, staging);
    count_kernel<<<NBKT, 256, 0, stream>>>(g_cur, staging, cnt);
    scanA_kernel<<<NB, 1024, 0, stream>>>(cnt, pre, bsum);
    scanB_kernel<<<1, 128, 0, stream>>>(bsum, bbase, offs);
    scanC_kernel<<<NB, 1024, 0, stream>>>(pre, bbase, offs);
    sort_kernel<<<NBKT, 256, 0, stream>>>(g_cur, staging, offs, pairs);

    conv_kernel<<<(NN * 192 + 255) / 256, 256, 0, stream>>>((const float2*)x, xh);

    gather_kernel<<<(NN / GPB) * 8, 256, 0, stream>>>(xh, pairs, offs, cnt, agg);

    matmul_kernel<<<NN / GPM, 384, 0, stream>>>(agg, W[0], W[1], W[2], W[3], bias, out);
}

// Round 16
// 425.858 us; speedup vs baseline: 1.0193x; 1.0193x over previous
//
#include <hip/hip_runtime.h>
#include <hip/hip_fp16.h>

#define NN 30000
#define NE 480000
#define CC 32
#define TT 12
#define CT 384            /* C*T */
#define TOT (4 * NN)      /* 120000 tasks */
#define NB  118           /* ceil(TOT/1024) */
#define NSL 8             /* slices per row (96 B data in 128-B slot) */
#define SLB ((size_t)NN * 128)   /* 3.84 MB xh slice array (padded slots) */
#define AGS ((size_t)TOT * 96)   /* 11.52 MB agg slice array (compact 96-B rows) */
#define GPB 8             /* nodes per gather block */
#define GPM 8             /* nodes per matmul block */
#define RSH2 193          /* matmul LDS row stride in half2 (padded) */
#define NBKT 235          /* CSR buckets: 512 rows each */
#define BCAP 16384        /* staging records per bucket */
#define PAIRS_WORDS ((size_t)4 * NE + 4 * TOT + 32)

typedef unsigned int u32x4 __attribute__((ext_vector_type(4)));
typedef unsigned int u32x2 __attribute__((ext_vector_type(2)));
typedef float f32x2 __attribute__((ext_vector_type(2)));

static __device__ __forceinline__ unsigned int h2u(__half2 h) {
    return __builtin_bit_cast(unsigned int, h);
}
static __device__ __forceinline__ __half2 u2h(unsigned int u) {
    return __builtin_bit_cast(__half2, u);
}

// ---------------- x -> fp16, slice-major, 128-B padded slots (96 B data) ----------------
// half2 word w (0..191) of row n -> slice s = w/24; slot byte offset n*128 + (w%24)*4.

__global__ void conv_kernel(const float2* __restrict__ x2, char* __restrict__ xh) {
    int i = blockIdx.x * blockDim.x + threadIdx.x;
    if (i < NN * 192) {
        float2 v = x2[i];
        int n = i / 192, w = i % 192;
        __half2* dst = (__half2*)(xh + (size_t)(w / 24) * SLB);
        dst[n * 32 + (w % 24)] = __floats2half2_rn(v.x, v.y);
    }
}

// ---------------- CSR build: binned, no random global writes ----------------

__global__ void initcur_kernel(int* __restrict__ g_cur) {
    int t = threadIdx.x;
    if (t < NBKT) g_cur[t] = t * BCAP;
}

__global__ __launch_bounds__(512)
void bin_kernel(const int* __restrict__ ei0, const int* __restrict__ ei1,
                const int* __restrict__ ei2, const int* __restrict__ ei3,
                const float* __restrict__ ew0, const float* __restrict__ ew1,
                const float* __restrict__ ew2, const float* __restrict__ ew3,
                int* __restrict__ g_cur, u32x2* __restrict__ staging) {
    __shared__ int bcnt[NBKT];
    __shared__ int bbase[NBKT];
    const int b = blockIdx.y;
    const int t = threadIdx.x;
    const int e0 = blockIdx.x * 4096;
    const int*   ei = (b == 0) ? ei0 : (b == 1) ? ei1 : (b == 2) ? ei2 : ei3;
    const float* ew = (b == 0) ? ew0 : (b == 1) ? ew1 : (b == 2) ? ew2 : ew3;

    for (int i = t; i < NBKT; i += 512) bcnt[i] = 0;
    __syncthreads();

    int row_[8]; unsigned int pair_[8]; int bkt_[8]; int rank_[8];
#pragma unroll
    for (int i = 0; i < 8; ++i) {
        int e = e0 + i * 512 + t;
        row_[i] = -1;
        if (e < NE) {
            int dst = ei[NE + e];
            int src = ei[e];
            unsigned int w16 = (unsigned int)__half_as_ushort(__float2half_rn(ew[e]));
            row_[i]  = b * NN + dst;
            pair_[i] = (unsigned int)src | (w16 << 16);
            bkt_[i]  = row_[i] >> 9;
            rank_[i] = atomicAdd(&bcnt[bkt_[i]], 1);
        }
    }
    __syncthreads();
    for (int i = t; i < NBKT; i += 512) {
        int cc = bcnt[i];
        bbase[i] = (cc > 0) ? atomicAdd(&g_cur[i], cc) : 0;
    }
    __syncthreads();
#pragma unroll
    for (int i = 0; i < 8; ++i) {
        if (row_[i] >= 0) {
            int pos = bbase[bkt_[i]] + rank_[i];
            if (pos < (bkt_[i] + 1) * BCAP) {
                u32x2 rec; rec.x = (unsigned int)row_[i]; rec.y = pair_[i];
                staging[pos] = rec;
            }
        }
    }
}

__global__ __launch_bounds__(256)
void count_kernel(const int* __restrict__ g_cur, const u32x2* __restrict__ staging,
                  int* __restrict__ cnt) {
    __shared__ int hist[512];
    const int bkt = blockIdx.x;
    const int t = threadIdx.x;
    hist[t] = 0; hist[t + 256] = 0;
    __syncthreads();
    const int row0 = bkt << 9;
    const int n = g_cur[bkt] - bkt * BCAP;
    const u32x2* __restrict__ sg = staging + (size_t)bkt * BCAP;
    for (int i = t; i < n; i += 256)
        atomicAdd(&hist[(int)sg[i].x - row0], 1);
    __syncthreads();
    if (row0 + t < TOT)       cnt[row0 + t]       = hist[t];
    if (row0 + t + 256 < TOT) cnt[row0 + t + 256] = hist[t + 256];
}

// scans over counts padded to multiples of 4 (aligned u32x4 pair loads)
__global__ void scanA_kernel(const int* __restrict__ cnt,
                             int* __restrict__ pre, int* __restrict__ bsum) {
    __shared__ int s[1024];
    int tid = threadIdx.x;
    int i = blockIdx.x * 1024 + tid;
    int v = (i < TOT) ? ((cnt[i] + 3) & ~3) : 0;
    s[tid] = v;
    __syncthreads();
    for (int off = 1; off < 1024; off <<= 1) {
        int t = (tid >= off) ? s[tid - off] : 0;
        __syncthreads();
        s[tid] += t;
        __syncthreads();
    }
    if (i < TOT) pre[i] = s[tid] - v;
    if (tid == 1023) bsum[blockIdx.x] = s[1023];
}

__global__ void scanB_kernel(const int* __restrict__ bsum,
                             int* __restrict__ bbase, int* __restrict__ offs) {
    __shared__ int s[128];
    int tid = threadIdx.x;
    int v = (tid < NB) ? bsum[tid] : 0;
    s[tid] = v;
    __syncthreads();
    for (int off = 1; off < 128; off <<= 1) {
        int t = (tid >= off) ? s[tid - off] : 0;
        __syncthreads();
        s[tid] += t;
        __syncthreads();
    }
    if (tid < NB) bbase[tid] = s[tid] - v;
    if (tid == 127) offs[TOT] = s[127];
}

__global__ void scanC_kernel(const int* __restrict__ pre, const int* __restrict__ bbase,
                             int* __restrict__ offs) {
    int i = blockIdx.x * 1024 + threadIdx.x;
    if (i < TOT) offs[i] = bbase[blockIdx.x] + pre[i];
}

__global__ __launch_bounds__(256)
void sort_kernel(const int* __restrict__ g_cur, const u32x2* __restrict__ staging,
                 const int* __restrict__ offs, unsigned int* __restrict__ pairs) {
    __shared__ int cur[512];
    const int bkt = blockIdx.x;
    const int t = threadIdx.x;
    const int row0 = bkt << 9;
    cur[t]       = (row0 + t < TOT)       ? offs[row0 + t]       : 0;
    cur[t + 256] = (row0 + t + 256 < TOT) ? offs[row0 + t + 256] : 0;
    __syncthreads();
    const int n = g_cur[bkt] - bkt * BCAP;
    const u32x2* __restrict__ sg = staging + (size_t)bkt * BCAP;
    for (int i = t; i < n; i += 256) {
        u32x2 r = sg[i];
        int pos = atomicAdd(&cur[(int)r.x - row0], 1);
        pairs[pos] = r.y;
    }
}

// ---------------- XCD-pinned slice gather, aligned reads, XCD-exclusive writes ----------------
// slice = blockIdx.x & 7 (empirical blockIdx%8 -> XCD round-robin; perf heuristic only).
// xh slot = 128 B aligned -> every gather is one L2 line. agg is slice-major: all writes
// to agg slice s come only from blocks with (blockIdx&7)==s -> one XCD, no line ping-pong.
// wave = 8 octets; octet -> task (node, branch); lane l owns 12 B of the 96-B data.

__global__ __launch_bounds__(256, 8)
void gather_kernel(const char* __restrict__ xh, const unsigned int* __restrict__ pairs,
                   const int* __restrict__ offs, const int* __restrict__ cnt,
                   char* __restrict__ agg) {
    const int tid  = threadIdx.x;
    const int lane = tid & 63;
    const int o = lane >> 3, l = lane & 7;
    const int task = (tid >> 6) * 8 + o;                 // 0..31
    const int slice = blockIdx.x & 7;
    const int node = (blockIdx.x >> 3) * GPB + (task >> 2);
    const int branch = task & 3;
    const int row = branch * NN + node;
    const char* __restrict__ xs = xh + (size_t)slice * SLB + l * 12;

    const int beg = offs[row];
    const int c   = cnt[row];

    __half2 a0 = u2h(0), a1 = u2h(0), a2 = u2h(0);
    __half2 b0 = u2h(0), b1 = u2h(0), b2 = u2h(0);

    for (int eb = 0; eb < c; eb += 4) {
        u32x4 pw = __builtin_nontemporal_load((const u32x4*)(pairs + beg + eb));
#pragma unroll
        for (int u = 0; u < 4; ++u) {
            unsigned int w32 = (u == 0) ? pw.x : (u == 1) ? pw.y : (u == 2) ? pw.z : pw.w;
            if (eb + u < c) {
                const char* rp = xs + (size_t)(w32 & 0xFFFFu) * 128;
                uint3 v = *(const uint3*)rp;
                __half2 w2 = __half2half2(__ushort_as_half((unsigned short)(w32 >> 16)));
                if (u & 1) {
                    b0 = __hfma2(w2, u2h(v.x), b0);
                    b1 = __hfma2(w2, u2h(v.y), b1);
                    b2 = __hfma2(w2, u2h(v.z), b2);
                } else {
                    a0 = __hfma2(w2, u2h(v.x), a0);
                    a1 = __hfma2(w2, u2h(v.y), a1);
                    a2 = __hfma2(w2, u2h(v.z), a2);
                }
            }
        }
    }
    char* dst = agg + (size_t)slice * AGS + (size_t)row * 96 + l * 12;
    __builtin_nontemporal_store(h2u(__hadd2(a0, b0)), (unsigned int*)dst);
    __builtin_nontemporal_store(h2u(__hadd2(a1, b1)), (unsigned int*)(dst + 4));
    __builtin_nontemporal_store(h2u(__hadd2(a2, b2)), (unsigned int*)(dst + 8));
}

// ---------------- streaming matmul: out = bias + sum_b agg_b @ W_b ----------------
// agg slice s holds bytes [s*96,(s+1)*96) of each logical 768-B row ([c][t] halves).

__global__ __launch_bounds__(384)
void matmul_kernel(const char* __restrict__ agg,
                   const float* __restrict__ W0, const float* __restrict__ W1,
                   const float* __restrict__ W2, const float* __restrict__ W3,
                   const float* __restrict__ bias, float* __restrict__ out) {
    __shared__ __half2 aggB[32 * RSH2];   // ~24.7 KB
    const int tid = threadIdx.x;
    const int n0 = blockIdx.x * GPM;

    // stage 32 rows x 8 slices x 96 B; 768 chunks of 32 B over 384 thr x 2
#pragma unroll
    for (int k = 0; k < 2; ++k) {
        const int cidx = tid + 384 * k;
        const int r = cidx / 24;           // local row = g*4+b
        const int rem = cidx % 24;
        const int s = rem / 3, part = rem % 3;
        const size_t grow = (size_t)((r & 3) * NN + n0 + (r >> 2));
        const char* src = agg + (size_t)s * AGS + grow * 96 + part * 32;
        char* dst = (char*)(aggB + r * RSH2) + s * 96 + part * 32;
        u32x4 v0 = __builtin_nontemporal_load((const u32x4*)src);
        u32x4 v1 = __builtin_nontemporal_load((const u32x4*)(src + 16));
        *(u32x4*)dst = v0; *(u32x4*)(dst + 16) = v1;
    }
    __syncthreads();

    const float* Ws[4] = { W0, W1, W2, W3 };
    {
        const int g = tid / 48;
        const int rem = tid % 48;
        const int q = rem / 6;
        const int t2 = rem % 6;
        f32x2 acc[4];
#pragma unroll
        for (int i = 0; i < 4; ++i) { float bv = bias[q * 4 + i]; acc[i].x = bv; acc[i].y = bv; }
#pragma unroll
        for (int b = 0; b < 4; ++b) {
            const float* __restrict__ Wb = Ws[b];
            const __half2* __restrict__ aL = aggB + (g * 4 + b) * RSH2 + t2;
#pragma unroll
            for (int h = 0; h < 2; ++h) {
                float2 row[16];
#pragma unroll
                for (int kk = 0; kk < 16; ++kk)
                    row[kk] = __half22float2(aL[(h * 16 + kk) * 6]);
#pragma unroll
                for (int kk = 0; kk < 16; ++kk) {
#pragma unroll
                    for (int i = 0; i < 4; ++i) {
                        float w = Wb[(h * 16 + kk) * CC + q * 4 + i];
                        acc[i].x = fmaf(w, row[kk].x, acc[i].x);
                        acc[i].y = fmaf(w, row[kk].y, acc[i].y);
                    }
                }
            }
        }
#pragma unroll
        for (int i = 0; i < 4; ++i) {
            f32x2* dst = (f32x2*)&out[(size_t)(n0 + g) * CT + (q * 4 + i) * TT + 2 * t2];
            __builtin_nontemporal_store(acc[i], dst);
        }
    }
}

// ---------------- launch ----------------

extern "C" void kernel_launch(void* const* d_in, const int* in_sizes, int n_in,
                              void* d_out, int out_size, void* d_ws, size_t ws_size,
                              hipStream_t stream) {
    const float* x    = (const float*)d_in[0];
    const float* bias = (const float*)d_in[13];
    const int*   ei[4] = { (const int*)d_in[1], (const int*)d_in[4],
                           (const int*)d_in[7], (const int*)d_in[10] };
    const float* ew[4] = { (const float*)d_in[2], (const float*)d_in[5],
                           (const float*)d_in[8], (const float*)d_in[11] };
    const float* W[4]  = { (const float*)d_in[3], (const float*)d_in[6],
                           (const float*)d_in[9], (const float*)d_in[12] };
    float* out = (float*)d_out;

    char* ws = (char*)d_ws;
    size_t OFF_PAIRS = 0;                                     // padded pairs ~9.6 MB
    size_t OFF_XH    = OFF_PAIRS + PAIRS_WORDS * 4;           // 30.72 MB xh (8 padded slices)
    size_t OFF_AGG   = OFF_XH    + NSL * SLB;                 // 92.16 MB agg (8 slice arrays)
    size_t OFF_CNT   = OFF_AGG   + NSL * AGS;                 // TOT int
    size_t OFF_OFFS  = OFF_CNT   + (size_t)TOT * 4;           // TOT+1 int
    size_t OFF_PRE   = OFF_OFFS  + (size_t)(TOT + 1) * 4;     // TOT int
    size_t OFF_BSUM  = OFF_PRE   + (size_t)TOT * 4;           // 128 int
    size_t OFF_BBASE = OFF_BSUM  + (size_t)128 * 4;           // 128 int
    size_t OFF_GCUR  = OFF_BBASE + (size_t)128 * 4;           // NBKT int

    unsigned int* pairs = (unsigned int*)(ws + OFF_PAIRS);
    char*         xh    = ws + OFF_XH;
    char*         agg   = ws + OFF_AGG;
    u32x2*        staging = (u32x2*)(ws + OFF_AGG);           // overlay: dead before gather
    int* cnt   = (int*)(ws + OFF_CNT);
    int* offs  = (int*)(ws + OFF_OFFS);
    int* pre   = (int*)(ws + OFF_PRE);
    int* bsum  = (int*)(ws + OFF_BSUM);
    int* bbase = (int*)(ws + OFF_BBASE);
    int* g_cur = (int*)(ws + OFF_GCUR);

    initcur_kernel<<<1, 256, 0, stream>>>(g_cur);

    dim3 bg((NE + 4095) / 4096, 4);
    bin_kernel<<<bg, 512, 0, stream>>>(ei[0], ei[1], ei[2], ei[3],
                                       ew[0], ew[1], ew[2], ew[3],
                                       g_cur, staging);
    count_kernel<<<NBKT, 256, 0, stream>>>(g_cur, staging, cnt);
    scanA_kernel<<<NB, 1024, 0, stream>>>(cnt, pre, bsum);
    scanB_kernel<<<1, 128, 0, stream>>>(bsum, bbase, offs);
    scanC_kernel<<<NB, 1024, 0, stream>>>(pre, bbase, offs);
    sort_kernel<<<NBKT, 256, 0, stream>>>(g_cur, staging, offs, pairs);

    conv_kernel<<<(NN * 192 + 255) / 256, 256, 0, stream>>>((const float2*)x, xh);

    gather_kernel<<<(NN / GPB) * 8, 256, 0, stream>>>(xh, pairs, offs, cnt, agg);

    matmul_kernel<<<NN / GPM, 384, 0, stream>>>(agg, W[0], W[1], W[2], W[3], bias, out);
}

// Round 17
// 383.466 us; speedup vs baseline: 1.1320x; 1.1105x over previous
//
#include <hip/hip_runtime.h>
#include <hip/hip_fp16.h>

#define NN 30000
#define NE 480000
#define CC 32
#define TT 12
#define CT 384            /* C*T */
#define TOT (4 * NN)      /* 120000 tasks */
#define NB  118           /* ceil(TOT/1024) */
#define NSL 6             /* slices per row */
#define SLB ((size_t)NN * 128)   /* 3.84 MB per 128-B slice array */
#define GPB 8             /* nodes per gather block */
#define GPM 8             /* nodes per matmul block */
#define RSH2 193          /* matmul LDS row stride in half2 (padded) */
#define NBKT 235          /* CSR buckets: 512 rows each */
#define BCAP 16384        /* staging records per bucket */
#define PAIRS_WORDS ((size_t)4 * NE + 4 * TOT + 64)

typedef unsigned int u32x4 __attribute__((ext_vector_type(4)));
typedef unsigned int u32x2 __attribute__((ext_vector_type(2)));
typedef float f32x2 __attribute__((ext_vector_type(2)));

static __device__ __forceinline__ unsigned int h2u(__half2 h) {
    return __builtin_bit_cast(unsigned int, h);
}
static __device__ __forceinline__ __half2 u2h(unsigned int u) {
    return __builtin_bit_cast(__half2, u);
}

// ---------------- x -> fp16, slice-major (6 slices x 128 B per node row) ----------------

__global__ void conv_kernel(const float2* __restrict__ x2, char* __restrict__ xh) {
    int i = blockIdx.x * blockDim.x + threadIdx.x;
    if (i < NN * 192) {
        float2 v = x2[i];
        int n = i / 192, w = i % 192;            // w = half2 index within row
        __half2* dst = (__half2*)(xh + (size_t)(w >> 5) * SLB);
        dst[n * 32 + (w & 31)] = __floats2half2_rn(v.x, v.y);
    }
}

// ---------------- CSR build: binned, no random global writes ----------------

__global__ void initcur_kernel(int* __restrict__ g_cur) {
    int t = threadIdx.x;
    if (t < NBKT) g_cur[t] = t * BCAP;
}

__global__ __launch_bounds__(512)
void bin_kernel(const int* __restrict__ ei0, const int* __restrict__ ei1,
                const int* __restrict__ ei2, const int* __restrict__ ei3,
                const float* __restrict__ ew0, const float* __restrict__ ew1,
                const float* __restrict__ ew2, const float* __restrict__ ew3,
                int* __restrict__ g_cur, u32x2* __restrict__ staging) {
    __shared__ int bcnt[NBKT];
    __shared__ int bbs[NBKT];
    const int b = blockIdx.y;
    const int t = threadIdx.x;
    const int e0 = blockIdx.x * 4096;
    const int*   ei = (b == 0) ? ei0 : (b == 1) ? ei1 : (b == 2) ? ei2 : ei3;
    const float* ew = (b == 0) ? ew0 : (b == 1) ? ew1 : (b == 2) ? ew2 : ew3;

    for (int i = t; i < NBKT; i += 512) bcnt[i] = 0;
    __syncthreads();

    int row_[8]; unsigned int pair_[8]; int bkt_[8]; int rank_[8];
#pragma unroll
    for (int i = 0; i < 8; ++i) {
        int e = e0 + i * 512 + t;
        row_[i] = -1;
        if (e < NE) {
            int dst = ei[NE + e];
            int src = ei[e];
            unsigned int w16 = (unsigned int)__half_as_ushort(__float2half_rn(ew[e]));
            row_[i]  = b * NN + dst;
            pair_[i] = (unsigned int)src | (w16 << 16);
            bkt_[i]  = row_[i] >> 9;
            rank_[i] = atomicAdd(&bcnt[bkt_[i]], 1);
        }
    }
    __syncthreads();
    for (int i = t; i < NBKT; i += 512) {
        int cc = bcnt[i];
        bbs[i] = (cc > 0) ? atomicAdd(&g_cur[i], cc) : 0;
    }
    __syncthreads();
#pragma unroll
    for (int i = 0; i < 8; ++i) {
        if (row_[i] >= 0) {
            int pos = bbs[bkt_[i]] + rank_[i];
            if (pos < (bkt_[i] + 1) * BCAP) {
                u32x2 rec; rec.x = (unsigned int)row_[i]; rec.y = pair_[i];
                staging[pos] = rec;
            }
        }
    }
}

// ---- fused count + scan + sort: 235 co-resident blocks, spin grid barriers ----

static __device__ __forceinline__ void gridbar(int* ctr) {
    __syncthreads();
    if (threadIdx.x == 0) {
        __threadfence();
        atomicAdd(ctr, 1);
        while (__hip_atomic_load(ctr, __ATOMIC_ACQUIRE, __HIP_MEMORY_SCOPE_AGENT) < NBKT) { }
    }
    __syncthreads();
}

__global__ __launch_bounds__(256)
void build_kernel(const int* __restrict__ g_cur, const u32x2* __restrict__ staging,
                  int* __restrict__ cnt, int* __restrict__ pre, int* __restrict__ bsum,
                  int* __restrict__ bbase, int* __restrict__ offs,
                  unsigned int* __restrict__ pairs, int* __restrict__ bar) {
    __shared__ int lds[512];
    const int bkt = blockIdx.x;
    const int t = threadIdx.x;
    const int row0 = bkt << 9;
    const int n = g_cur[bkt] - bkt * BCAP;
    const u32x2* __restrict__ sg = staging + (size_t)bkt * BCAP;

    // ---- phase A: per-bucket histogram -> cnt ----
    lds[t] = 0; lds[t + 256] = 0;
    __syncthreads();
    for (int i = t; i < n; i += 256)
        atomicAdd(&lds[(int)sg[i].x - row0], 1);
    __syncthreads();
    if (row0 + t < TOT)       cnt[row0 + t]       = lds[t];
    if (row0 + t + 256 < TOT) cnt[row0 + t + 256] = lds[t + 256];
    gridbar(&bar[0]);

    // ---- phase B: blocks 0..117 scan 1024-chunks of padded counts ----
    if (bkt < NB) {
        const int base = bkt * 1024;
        int v[4]; int s = 0;
#pragma unroll
        for (int j = 0; j < 4; ++j) {
            int idx = base + 4 * t + j;
            v[j] = (idx < TOT) ? ((cnt[idx] + 3) & ~3) : 0;
            s += v[j];
        }
        lds[t] = s;
        __syncthreads();
        for (int off = 1; off < 256; off <<= 1) {
            int x = (t >= off) ? lds[t - off] : 0;
            __syncthreads();
            lds[t] += x;
            __syncthreads();
        }
        int excl = (t == 0) ? 0 : lds[t - 1];
#pragma unroll
        for (int j = 0; j < 4; ++j) {
            int idx = base + 4 * t + j;
            if (idx < TOT) pre[idx] = excl;
            excl += v[j];
        }
        if (t == 255) bsum[bkt] = lds[255];
    }
    gridbar(&bar[1]);

    // ---- phase C: block 0 scans the 118 block sums ----
    if (bkt == 0) {
        int v = (t < NB) ? bsum[t] : 0;
        lds[t] = v;
        __syncthreads();
        for (int off = 1; off < 256; off <<= 1) {
            int x = (t >= off) ? lds[t - off] : 0;
            __syncthreads();
            lds[t] += x;
            __syncthreads();
        }
        if (t < NB) bbase[t] = lds[t] - v;
    }
    gridbar(&bar[2]);

    // ---- phase D: compute offs (scanC folded in) + bucket-local sort ----
#pragma unroll
    for (int k = 0; k < 2; ++k) {
        int r = row0 + t + 256 * k;
        int o = 0;
        if (r < TOT) o = bbase[r >> 10] + pre[r];
        lds[t + 256 * k] = o;
        if (r < TOT) offs[r] = o;
    }
    __syncthreads();
    for (int i = t; i < n; i += 256) {
        u32x2 r = sg[i];
        int pos = atomicAdd(&lds[(int)r.x - row0], 1);
        pairs[pos] = r.y;
    }
}

// ---------------- slice-resident gather (R11 structure, unmodified) ----------------
// grid (NN/GPB, NSL): blockIdx.y = slice (slowest-varying -> one 3.84 MB slice in flight).
// wave = 8 octets; octet -> task (node, branch); lane l owns 16 B of the 128-B slice row.

__global__ __launch_bounds__(256, 8)
void gather_kernel(const char* __restrict__ xh, const unsigned int* __restrict__ pairs,
                   const int* __restrict__ offs, const int* __restrict__ cnt,
                   char* __restrict__ agg) {
    const int tid  = threadIdx.x;
    const int lane = tid & 63;
    const int o = lane >> 3, l = lane & 7;
    const int task = (tid >> 6) * 8 + o;                 // 0..31
    const int node = blockIdx.x * GPB + (task >> 2);
    const int branch = task & 3;
    const int row = branch * NN + node;
    const int slice = blockIdx.y;
    const char* __restrict__ xs = xh + (size_t)slice * SLB + l * 16;

    const int beg = offs[row];
    const int c   = cnt[row];

    __half2 a0 = u2h(0), a1 = u2h(0), a2 = u2h(0), a3 = u2h(0);
    __half2 b0 = u2h(0), b1 = u2h(0), b2 = u2h(0), b3 = u2h(0);

    for (int eb = 0; eb < c; eb += 4) {
        u32x4 pw = __builtin_nontemporal_load((const u32x4*)(pairs + beg + eb));
#pragma unroll
        for (int u = 0; u < 4; ++u) {
            unsigned int w32 = (u == 0) ? pw.x : (u == 1) ? pw.y : (u == 2) ? pw.z : pw.w;
            if (eb + u < c) {
                u32x4 xv = *(const u32x4*)(xs + (size_t)(w32 & 0xFFFFu) * 128);
                __half2 w2 = __half2half2(__ushort_as_half((unsigned short)(w32 >> 16)));
                if (u & 1) {
                    b0 = __hfma2(w2, u2h(xv.x), b0);
                    b1 = __hfma2(w2, u2h(xv.y), b1);
                    b2 = __hfma2(w2, u2h(xv.z), b2);
                    b3 = __hfma2(w2, u2h(xv.w), b3);
                } else {
                    a0 = __hfma2(w2, u2h(xv.x), a0);
                    a1 = __hfma2(w2, u2h(xv.y), a1);
                    a2 = __hfma2(w2, u2h(xv.z), a2);
                    a3 = __hfma2(w2, u2h(xv.w), a3);
                }
            }
        }
    }
    u32x4 r;
    r.x = h2u(__hadd2(a0, b0));
    r.y = h2u(__hadd2(a1, b1));
    r.z = h2u(__hadd2(a2, b2));
    r.w = h2u(__hadd2(a3, b3));
    __builtin_nontemporal_store(r, (u32x4*)(agg + (size_t)row * 768 + slice * 128 + l * 16));
}

// ---------------- streaming matmul: out = bias + sum_b agg_b @ W_b ----------------

__global__ __launch_bounds__(384)
void matmul_kernel(const char* __restrict__ agg,
                   const float* __restrict__ W0, const float* __restrict__ W1,
                   const float* __restrict__ W2, const float* __restrict__ W3,
                   const float* __restrict__ bias, float* __restrict__ out) {
    __shared__ __half2 aggB[32 * RSH2];   // ~24.7 KB
    const int tid = threadIdx.x;
    const int n0 = blockIdx.x * GPM;

    {
        const int r = tid / 12, sub = tid % 12;
        const char* src = agg + (size_t)((r & 3) * NN + n0 + (r >> 2)) * 768 + sub * 64;
        char* dst = (char*)(aggB + r * RSH2) + sub * 64;
#pragma unroll
        for (int q = 0; q < 4; ++q) {
            u32x4 v = __builtin_nontemporal_load((const u32x4*)(src + 16 * q));
            *(u32x4*)(dst + 16 * q) = v;
        }
    }
    __syncthreads();

    const float* Ws[4] = { W0, W1, W2, W3 };
    {
        const int g = tid / 48;
        const int rem = tid % 48;
        const int q = rem / 6;
        const int t2 = rem % 6;
        f32x2 acc[4];
#pragma unroll
        for (int i = 0; i < 4; ++i) { float bv = bias[q * 4 + i]; acc[i].x = bv; acc[i].y = bv; }
#pragma unroll
        for (int b = 0; b < 4; ++b) {
            const float* __restrict__ Wb = Ws[b];
            const __half2* __restrict__ aL = aggB + (g * 4 + b) * RSH2 + t2;
#pragma unroll
            for (int h = 0; h < 2; ++h) {
                float2 row[16];
#pragma unroll
                for (int kk = 0; kk < 16; ++kk)
                    row[kk] = __half22float2(aL[(h * 16 + kk) * 6]);
#pragma unroll
                for (int kk = 0; kk < 16; ++kk) {
#pragma unroll
                    for (int i = 0; i < 4; ++i) {
                        float w = Wb[(h * 16 + kk) * CC + q * 4 + i];
                        acc[i].x = fmaf(w, row[kk].x, acc[i].x);
                        acc[i].y = fmaf(w, row[kk].y, acc[i].y);
                    }
                }
            }
        }
#pragma unroll
        for (int i = 0; i < 4; ++i) {
            f32x2* dst = (f32x2*)&out[(size_t)(n0 + g) * CT + (q * 4 + i) * TT + 2 * t2];
            __builtin_nontemporal_store(acc[i], dst);
        }
    }
}

// ---------------- launch ----------------

extern "C" void kernel_launch(void* const* d_in, const int* in_sizes, int n_in,
                              void* d_out, int out_size, void* d_ws, size_t ws_size,
                              hipStream_t stream) {
    const float* x    = (const float*)d_in[0];
    const float* bias = (const float*)d_in[13];
    const int*   ei[4] = { (const int*)d_in[1], (const int*)d_in[4],
                           (const int*)d_in[7], (const int*)d_in[10] };
    const float* ew[4] = { (const float*)d_in[2], (const float*)d_in[5],
                           (const float*)d_in[8], (const float*)d_in[11] };
    const float* W[4]  = { (const float*)d_in[3], (const float*)d_in[6],
                           (const float*)d_in[9], (const float*)d_in[12] };
    float* out = (float*)d_out;

    char* ws = (char*)d_ws;
    size_t OFF_PAIRS = 0;                                     // padded pairs ~9.6 MB
    size_t OFF_XH    = OFF_PAIRS + PAIRS_WORDS * 4;           // 23.04 MB fp16 x
    size_t OFF_AGG   = OFF_XH    + NSL * SLB;                 // 92.16 MB agg (staging overlay)
    size_t OFF_CNT   = OFF_AGG   + (size_t)TOT * 768;         // TOT int
    size_t OFF_OFFS  = OFF_CNT   + (size_t)TOT * 4;           // TOT+1 int
    size_t OFF_PRE   = OFF_OFFS  + (size_t)(TOT + 1) * 4;     // TOT int
    size_t OFF_BSUM  = OFF_PRE   + (size_t)TOT * 4;           // 128 int
    size_t OFF_BBASE = OFF_BSUM  + (size_t)128 * 4;           // 128 int
    size_t OFF_GCUR  = OFF_BBASE + (size_t)128 * 4;           // NBKT int
    size_t OFF_BAR   = OFF_GCUR  + (size_t)256 * 4;           // 4 int

    unsigned int* pairs = (unsigned int*)(ws + OFF_PAIRS);
    char*         xh    = ws + OFF_XH;
    char*         agg   = ws + OFF_AGG;
    u32x2*        staging = (u32x2*)(ws + OFF_AGG);           // overlay: dead before gather
    int* cnt   = (int*)(ws + OFF_CNT);
    int* offs  = (int*)(ws + OFF_OFFS);
    int* pre   = (int*)(ws + OFF_PRE);
    int* bsum  = (int*)(ws + OFF_BSUM);
    int* bbase = (int*)(ws + OFF_BBASE);
    int* g_cur = (int*)(ws + OFF_GCUR);
    int* bar   = (int*)(ws + OFF_BAR);

    hipMemsetAsync(bar, 0, 16, stream);

    initcur_kernel<<<1, 256, 0, stream>>>(g_cur);

    dim3 bg((NE + 4095) / 4096, 4);
    bin_kernel<<<bg, 512, 0, stream>>>(ei[0], ei[1], ei[2], ei[3],
                                       ew[0], ew[1], ew[2], ew[3],
                                       g_cur, staging);

    build_kernel<<<NBKT, 256, 0, stream>>>(g_cur, staging, cnt, pre, bsum,
                                           bbase, offs, pairs, bar);

    conv_kernel<<<(NN * 192 + 255) / 256, 256, 0, stream>>>((const float2*)x, xh);

    dim3 gg(NN / GPB, NSL);
    gather_kernel<<<gg, 256, 0, stream>>>(xh, pairs, offs, cnt, agg);

    matmul_kernel<<<NN / GPM, 384, 0, stream>>>(agg, W[0], W[1], W[2], W[3], bias, out);
}

// Round 18
// 294.871 us; speedup vs baseline: 1.4721x; 1.3005x over previous
//
#include <hip/hip_runtime.h>
#include <hip/hip_fp16.h>

#define NN 30000
#define NE 480000
#define CC 32
#define TT 12
#define CT 384            /* C*T */
#define TOT (4 * NN)      /* 120000 tasks */
#define NB  118           /* ceil(TOT/1024) */
#define NSL 6             /* slices per row */
#define SLB ((size_t)NN * 128)   /* 3.84 MB per 128-B slice array */
#define GPB 8             /* nodes per gather block */
#define GPM 8             /* nodes per matmul block */
#define RSH2 193          /* matmul LDS row stride in half2 (padded) */
#define NBKT 235          /* CSR buckets: 512 rows each */
#define BCAP 16384        /* staging records per bucket */
#define PAIRS_WORDS ((size_t)4 * NE + 4 * TOT + 32)

typedef unsigned int u32x4 __attribute__((ext_vector_type(4)));
typedef unsigned int u32x2 __attribute__((ext_vector_type(2)));
typedef float f32x2 __attribute__((ext_vector_type(2)));

static __device__ __forceinline__ unsigned int h2u(__half2 h) {
    return __builtin_bit_cast(unsigned int, h);
}
static __device__ __forceinline__ __half2 u2h(unsigned int u) {
    return __builtin_bit_cast(__half2, u);
}

// ---------------- x -> fp16, slice-major (6 slices x 128 B per node row) ----------------

__global__ void conv_kernel(const float2* __restrict__ x2, char* __restrict__ xh) {
    int i = blockIdx.x * blockDim.x + threadIdx.x;
    if (i < NN * 192) {
        float2 v = x2[i];
        int n = i / 192, w = i % 192;            // w = half2 index within row
        __half2* dst = (__half2*)(xh + (size_t)(w >> 5) * SLB);
        dst[n * 32 + (w & 31)] = __floats2half2_rn(v.x, v.y);
    }
}

// ---------------- CSR build: binned, no random global writes (R11 structure) ----------------

__global__ void initcur_kernel(int* __restrict__ g_cur) {
    int t = threadIdx.x;
    if (t < NBKT) g_cur[t] = t * BCAP;
}

__global__ __launch_bounds__(512)
void bin_kernel(const int* __restrict__ ei0, const int* __restrict__ ei1,
                const int* __restrict__ ei2, const int* __restrict__ ei3,
                const float* __restrict__ ew0, const float* __restrict__ ew1,
                const float* __restrict__ ew2, const float* __restrict__ ew3,
                int* __restrict__ g_cur, u32x2* __restrict__ staging) {
    __shared__ int bcnt[NBKT];
    __shared__ int bbs[NBKT];
    const int b = blockIdx.y;
    const int t = threadIdx.x;
    const int e0 = blockIdx.x * 4096;
    const int*   ei = (b == 0) ? ei0 : (b == 1) ? ei1 : (b == 2) ? ei2 : ei3;
    const float* ew = (b == 0) ? ew0 : (b == 1) ? ew1 : (b == 2) ? ew2 : ew3;

    for (int i = t; i < NBKT; i += 512) bcnt[i] = 0;
    __syncthreads();

    int row_[8]; unsigned int pair_[8]; int bkt_[8]; int rank_[8];
#pragma unroll
    for (int i = 0; i < 8; ++i) {
        int e = e0 + i * 512 + t;
        row_[i] = -1;
        if (e < NE) {
            int dst = ei[NE + e];
            int src = ei[e];
            unsigned int w16 = (unsigned int)__half_as_ushort(__float2half_rn(ew[e]));
            row_[i]  = b * NN + dst;
            pair_[i] = (unsigned int)src | (w16 << 16);
            bkt_[i]  = row_[i] >> 9;
            rank_[i] = atomicAdd(&bcnt[bkt_[i]], 1);
        }
    }
    __syncthreads();
    for (int i = t; i < NBKT; i += 512) {
        int cc = bcnt[i];
        bbs[i] = (cc > 0) ? atomicAdd(&g_cur[i], cc) : 0;
    }
    __syncthreads();
#pragma unroll
    for (int i = 0; i < 8; ++i) {
        if (row_[i] >= 0) {
            int pos = bbs[bkt_[i]] + rank_[i];
            if (pos < (bkt_[i] + 1) * BCAP) {
                u32x2 rec; rec.x = (unsigned int)row_[i]; rec.y = pair_[i];
                staging[pos] = rec;
            }
        }
    }
}

__global__ __launch_bounds__(256)
void count_kernel(const int* __restrict__ g_cur, const u32x2* __restrict__ staging,
                  int* __restrict__ cnt) {
    __shared__ int hist[512];
    const int bkt = blockIdx.x;
    const int t = threadIdx.x;
    hist[t] = 0; hist[t + 256] = 0;
    __syncthreads();
    const int row0 = bkt << 9;
    const int n = g_cur[bkt] - bkt * BCAP;
    const u32x2* __restrict__ sg = staging + (size_t)bkt * BCAP;
    for (int i = t; i < n; i += 256)
        atomicAdd(&hist[(int)sg[i].x - row0], 1);
    __syncthreads();
    if (row0 + t < TOT)       cnt[row0 + t]       = hist[t];
    if (row0 + t + 256 < TOT) cnt[row0 + t + 256] = hist[t + 256];
}

// scans over counts padded to multiples of 4 (aligned u32x4 pair loads)
__global__ void scanA_kernel(const int* __restrict__ cnt,
                             int* __restrict__ pre, int* __restrict__ bsum) {
    __shared__ int s[1024];
    int tid = threadIdx.x;
    int i = blockIdx.x * 1024 + tid;
    int v = (i < TOT) ? ((cnt[i] + 3) & ~3) : 0;
    s[tid] = v;
    __syncthreads();
    for (int off = 1; off < 1024; off <<= 1) {
        int t = (tid >= off) ? s[tid - off] : 0;
        __syncthreads();
        s[tid] += t;
        __syncthreads();
    }
    if (i < TOT) pre[i] = s[tid] - v;
    if (tid == 1023) bsum[blockIdx.x] = s[1023];
}

__global__ void scanB_kernel(const int* __restrict__ bsum,
                             int* __restrict__ bbase, int* __restrict__ offs) {
    __shared__ int s[128];
    int tid = threadIdx.x;
    int v = (tid < NB) ? bsum[tid] : 0;
    s[tid] = v;
    __syncthreads();
    for (int off = 1; off < 128; off <<= 1) {
        int t = (tid >= off) ? s[tid - off] : 0;
        __syncthreads();
        s[tid] += t;
        __syncthreads();
    }
    if (tid < NB) bbase[tid] = s[tid] - v;
    if (tid == 127) offs[TOT] = s[127];
}

// sort with folded offs computation (replaces scanC + R11 sort)
__global__ __launch_bounds__(256)
void sort_kernel(const int* __restrict__ g_cur, const u32x2* __restrict__ staging,
                 const int* __restrict__ pre, const int* __restrict__ bbase,
                 int* __restrict__ offs, unsigned int* __restrict__ pairs) {
    __shared__ int cur[512];
    const int bkt = blockIdx.x;
    const int t = threadIdx.x;
    const int row0 = bkt << 9;
#pragma unroll
    for (int k = 0; k < 2; ++k) {
        int r = row0 + t + 256 * k;
        int o = 0;
        if (r < TOT) {
            o = bbase[r >> 10] + pre[r];
            offs[r] = o;
        }
        cur[t + 256 * k] = o;
    }
    __syncthreads();
    const int n = g_cur[bkt] - bkt * BCAP;
    const u32x2* __restrict__ sg = staging + (size_t)bkt * BCAP;
    for (int i = t; i < n; i += 256) {
        u32x2 r = sg[i];
        int pos = atomicAdd(&cur[(int)r.x - row0], 1);
        pairs[pos] = r.y;
    }
}

// ---------------- slice-resident gather (R11 exact: plain pairs loads) ----------------
// grid (NN/GPB, NSL): blockIdx.y = slice (slowest-varying -> one 3.84 MB slice in flight).
// wave = 8 octets; octet -> task (node, branch); lane l owns 16 B of the 128-B slice row.

__global__ __launch_bounds__(256, 8)
void gather_kernel(const char* __restrict__ xh, const unsigned int* __restrict__ pairs,
                   const int* __restrict__ offs, const int* __restrict__ cnt,
                   char* __restrict__ agg) {
    const int tid  = threadIdx.x;
    const int lane = tid & 63;
    const int o = lane >> 3, l = lane & 7;
    const int task = (tid >> 6) * 8 + o;                 // 0..31
    const int node = blockIdx.x * GPB + (task >> 2);
    const int branch = task & 3;
    const int row = branch * NN + node;
    const int slice = blockIdx.y;
    const char* __restrict__ xs = xh + (size_t)slice * SLB + l * 16;

    const int beg = offs[row];
    const int c   = cnt[row];

    __half2 a0 = u2h(0), a1 = u2h(0), a2 = u2h(0), a3 = u2h(0);
    __half2 b0 = u2h(0), b1 = u2h(0), b2 = u2h(0), b3 = u2h(0);

    for (int eb = 0; eb < c; eb += 4) {
        u32x4 pw = *(const u32x4*)(pairs + beg + eb);    // aligned: beg%4==0 (plain load)
#pragma unroll
        for (int u = 0; u < 4; ++u) {
            unsigned int w32 = (u == 0) ? pw.x : (u == 1) ? pw.y : (u == 2) ? pw.z : pw.w;
            if (eb + u < c) {
                u32x4 xv = *(const u32x4*)(xs + (size_t)(w32 & 0xFFFFu) * 128);
                __half2 w2 = __half2half2(__ushort_as_half((unsigned short)(w32 >> 16)));
                if (u & 1) {
                    b0 = __hfma2(w2, u2h(xv.x), b0);
                    b1 = __hfma2(w2, u2h(xv.y), b1);
                    b2 = __hfma2(w2, u2h(xv.z), b2);
                    b3 = __hfma2(w2, u2h(xv.w), b3);
                } else {
                    a0 = __hfma2(w2, u2h(xv.x), a0);
                    a1 = __hfma2(w2, u2h(xv.y), a1);
                    a2 = __hfma2(w2, u2h(xv.z), a2);
                    a3 = __hfma2(w2, u2h(xv.w), a3);
                }
            }
        }
    }
    u32x4 r;
    r.x = h2u(__hadd2(a0, b0));
    r.y = h2u(__hadd2(a1, b1));
    r.z = h2u(__hadd2(a2, b2));
    r.w = h2u(__hadd2(a3, b3));
    __builtin_nontemporal_store(r, (u32x4*)(agg + (size_t)row * 768 + slice * 128 + l * 16));
}

// ---------------- streaming matmul: out = bias + sum_b agg_b @ W_b ----------------

__global__ __launch_bounds__(384)
void matmul_kernel(const char* __restrict__ agg,
                   const float* __restrict__ W0, const float* __restrict__ W1,
                   const float* __restrict__ W2, const float* __restrict__ W3,
                   const float* __restrict__ bias, float* __restrict__ out) {
    __shared__ __half2 aggB[32 * RSH2];   // ~24.7 KB
    const int tid = threadIdx.x;
    const int n0 = blockIdx.x * GPM;

    {
        const int r = tid / 12, sub = tid % 12;
        const char* src = agg + (size_t)((r & 3) * NN + n0 + (r >> 2)) * 768 + sub * 64;
        char* dst = (char*)(aggB + r * RSH2) + sub * 64;
#pragma unroll
        for (int q = 0; q < 4; ++q) {
            u32x4 v = __builtin_nontemporal_load((const u32x4*)(src + 16 * q));
            *(u32x4*)(dst + 16 * q) = v;
        }
    }
    __syncthreads();

    const float* Ws[4] = { W0, W1, W2, W3 };
    {
        const int g = tid / 48;
        const int rem = tid % 48;
        const int q = rem / 6;
        const int t2 = rem % 6;
        f32x2 acc[4];
#pragma unroll
        for (int i = 0; i < 4; ++i) { float bv = bias[q * 4 + i]; acc[i].x = bv; acc[i].y = bv; }
#pragma unroll
        for (int b = 0; b < 4; ++b) {
            const float* __restrict__ Wb = Ws[b];
            const __half2* __restrict__ aL = aggB + (g * 4 + b) * RSH2 + t2;
#pragma unroll
            for (int h = 0; h < 2; ++h) {
                float2 row[16];
#pragma unroll
                for (int kk = 0; kk < 16; ++kk)
                    row[kk] = __half22float2(aL[(h * 16 + kk) * 6]);
#pragma unroll
                for (int kk = 0; kk < 16; ++kk) {
#pragma unroll
                    for (int i = 0; i < 4; ++i) {
                        float w = Wb[(h * 16 + kk) * CC + q * 4 + i];
                        acc[i].x = fmaf(w, row[kk].x, acc[i].x);
                        acc[i].y = fmaf(w, row[kk].y, acc[i].y);
                    }
                }
            }
        }
#pragma unroll
        for (int i = 0; i < 4; ++i) {
            f32x2* dst = (f32x2*)&out[(size_t)(n0 + g) * CT + (q * 4 + i) * TT + 2 * t2];
            __builtin_nontemporal_store(acc[i], dst);
        }
    }
}

// ---------------- launch ----------------

extern "C" void kernel_launch(void* const* d_in, const int* in_sizes, int n_in,
                              void* d_out, int out_size, void* d_ws, size_t ws_size,
                              hipStream_t stream) {
    const float* x    = (const float*)d_in[0];
    const float* bias = (const float*)d_in[13];
    const int*   ei[4] = { (const int*)d_in[1], (const int*)d_in[4],
                           (const int*)d_in[7], (const int*)d_in[10] };
    const float* ew[4] = { (const float*)d_in[2], (const float*)d_in[5],
                           (const float*)d_in[8], (const float*)d_in[11] };
    const float* W[4]  = { (const float*)d_in[3], (const float*)d_in[6],
                           (const float*)d_in[9], (const float*)d_in[12] };
    float* out = (float*)d_out;

    char* ws = (char*)d_ws;
    size_t OFF_PAIRS = 0;                                     // padded pairs ~9.6 MB
    size_t OFF_XH    = OFF_PAIRS + PAIRS_WORDS * 4;           // 23.04 MB fp16 x
    size_t OFF_AGG   = OFF_XH    + NSL * SLB;                 // 92.16 MB agg (staging overlay)
    size_t OFF_CNT   = OFF_AGG   + (size_t)TOT * 768;         // TOT int
    size_t OFF_OFFS  = OFF_CNT   + (size_t)TOT * 4;           // TOT+1 int
    size_t OFF_PRE   = OFF_OFFS  + (size_t)(TOT + 1) * 4;     // TOT int
    size_t OFF_BSUM  = OFF_PRE   + (size_t)TOT * 4;           // 128 int
    size_t OFF_BBASE = OFF_BSUM  + (size_t)128 * 4;           // 128 int
    size_t OFF_GCUR  = OFF_BBASE + (size_t)128 * 4;           // NBKT int

    unsigned int* pairs = (unsigned int*)(ws + OFF_PAIRS);
    char*         xh    = ws + OFF_XH;
    char*         agg   = ws + OFF_AGG;
    u32x2*        staging = (u32x2*)(ws + OFF_AGG);           // overlay: dead before gather
    int* cnt   = (int*)(ws + OFF_CNT);
    int* offs  = (int*)(ws + OFF_OFFS);
    int* pre   = (int*)(ws + OFF_PRE);
    int* bsum  = (int*)(ws + OFF_BSUM);
    int* bbase = (int*)(ws + OFF_BBASE);
    int* g_cur = (int*)(ws + OFF_GCUR);

    initcur_kernel<<<1, 256, 0, stream>>>(g_cur);

    dim3 bg((NE + 4095) / 4096, 4);
    bin_kernel<<<bg, 512, 0, stream>>>(ei[0], ei[1], ei[2], ei[3],
                                       ew[0], ew[1], ew[2], ew[3],
                                       g_cur, staging);
    count_kernel<<<NBKT, 256, 0, stream>>>(g_cur, staging, cnt);
    scanA_kernel<<<NB, 1024, 0, stream>>>(cnt, pre, bsum);
    scanB_kernel<<<1, 128, 0, stream>>>(bsum, bbase, offs);
    sort_kernel<<<NBKT, 256, 0, stream>>>(g_cur, staging, pre, bbase, offs, pairs);

    conv_kernel<<<(NN * 192 + 255) / 256, 256, 0, stream>>>((const float2*)x, xh);

    dim3 gg(NN / GPB, NSL);
    gather_kernel<<<gg, 256, 0, stream>>>(xh, pairs, offs, cnt, agg);

    matmul_kernel<<<NN / GPM, 384, 0, stream>>>(agg, W[0], W[1], W[2], W[3], bias, out);
}